// Round 1
// 255.888 us; speedup vs baseline: 1.0542x; 1.0542x over previous
//
#include <hip/hip_runtime.h>
#include <math.h>

#define BLOCK 256
#define F4PB (BLOCK * 9 / 4)   // 576 float4 tiles per block

__device__ __forceinline__ float frcp(float x)  { return __builtin_amdgcn_rcpf(x); }
__device__ __forceinline__ float frsq(float x)  { return __builtin_amdgcn_rsqf(x); }
__device__ __forceinline__ float fsqrt_r(float x){ return __builtin_amdgcn_sqrtf(x); }

// One-sided (Hestenes) Jacobi rotation on columns (p,q) of A only (no V).
// Squared column norms np, nq carried and updated analytically.
// de Rijk variant keeps np >= nq (descending order for free).
// Degenerate guard folded into a +1e-15 bias on ch: for normal data the bias
// is below f32 rounding; when del=rho=0 it forces (c,s)=(1,0) exactly like the
// old cmp+cndmask guard, 3 fewer instructions per rot.
__device__ __forceinline__ void rot(
    float& x0, float& x1, float& x2, float& np,
    float& y0, float& y1, float& y2, float& nq)
{
    float apq = fmaf(x0, y0, fmaf(x1, y1, x2 * y2));
    float del = np - nq;
    float rho = apq + apq;
    float r   = fsqrt_r(fmaf(del, del, rho * rho));   // raw v_sqrt_f32
    float ch  = fabsf(del) + r + 1e-15f;              // unnormalized cos (+bias)
    bool  sw  = del < 0.0f;                           // de Rijk: theta+90deg
    float sh  = sw ? -rho : rho;                      // unnormalized sin
    float inv = frsq(fmaf(ch, ch, sh * sh));          // nn >= 1e-30: always normal
    float c   = ch * inv;
    float s   = sh * inv;
    float cf  = sw ? -s : c;
    float sf  = sw ?  c : s;
    float t;
    t = x0; x0 = fmaf(cf, t, sf * y0); y0 = fmaf(cf, y0, -sf * t);
    t = x1; x1 = fmaf(cf, t, sf * y1); y1 = fmaf(cf, y1, -sf * t);
    t = x2; x2 = fmaf(cf, t, sf * y2); y2 = fmaf(cf, y2, -sf * t);
    float sum = np + nq;
    np = 0.5f * (sum + r);
    nq = fmaxf(0.5f * (sum - r), 0.0f);
}

__global__ __launch_bounds__(BLOCK) void dp_kernel(
    const float* __restrict__ F,
    const float* __restrict__ p_yml,
    const float* __restrict__ p_nu,
    const float* __restrict__ p_fa,
    const float* __restrict__ p_coh,
    float* __restrict__ out,
    int n_elem)
{
    __shared__ float lds[BLOCK * 9];
    const int t_id    = threadIdx.x;
    const int nfloats = n_elem * 9;                       // <= 36e6, fits int
    const int base_f  = (int)blockIdx.x * (BLOCK * 9);    // 32-bit addressing

    // ---- stage in: coalesced float4 ----
    #pragma unroll
    for (int j = 0; j < 3; ++j) {
        int idx = t_id + j * BLOCK;
        if (idx < F4PB) {
            int g4 = (base_f >> 2) + idx;
            int gf = g4 << 2;
            if (gf + 4 <= nfloats) {
                ((float4*)lds)[idx] = ((const float4*)F)[g4];
            } else {
                #pragma unroll
                for (int k = 0; k < 4; ++k)
                    if (gf + k < nfloats) lds[idx * 4 + k] = F[gf + k];
            }
        }
    }
    __syncthreads();

    const int  e     = (int)blockIdx.x * BLOCK + t_id;
    const bool valid = e < n_elem;

    // original A (kept for V recovery): aRC = row R, col C
    float a00, a01, a02, a10, a11, a12, a20, a21, a22;
    {
        const float* p = lds + t_id * 9;   // stride 9: 2-way bank alias only (free)
        a00 = p[0]; a01 = p[1]; a02 = p[2];
        a10 = p[3]; a11 = p[4]; a12 = p[5];
        a20 = p[6]; a21 = p[7]; a22 = p[8];
    }
    // NOTE: barrier for LDS reuse moved to just before output staging.

    // ---- material params (uniform) ----
    const float yml = p_yml[0];
    const float nu  = p_nu[0];
    const float fa  = p_fa[0];
    const float coh = p_coh[0];
    const float E     = __expf(yml);
    const float sphi  = __sinf(fa * 0.017453292519943295f);
    const float alpha = 1.632993161855452f * sphi * frcp(3.0f - sphi);
    const float mu    = E * 0.5f * frcp(1.0f + nu);
    const float la    = E * nu * frcp((1.0f + nu) * (1.0f - 2.0f * nu));
    const float ratio = (3.0f * la + 2.0f * mu) * frcp(2.0f * mu) * alpha;

    // ---- working copy of A's columns + squared norms ----
    float c00=a00, c10=a10, c20=a20;   // col 0
    float c01=a01, c11=a11, c21=a21;   // col 1
    float c02=a02, c12=a12, c22=a22;   // col 2
    float n0 = fmaf(c00,c00, fmaf(c10,c10, c20*c20));
    float n1 = fmaf(c01,c01, fmaf(c11,c11, c21*c21));
    float n2 = fmaf(c02,c02, fmaf(c12,c12, c22*c22));

    // ---- one-sided Jacobi, 4 cyclic sweeps (no V accumulation) ----
    #pragma unroll
    for (int sweep = 0; sweep < 4; ++sweep) {
        rot(c00,c10,c20,n0, c01,c11,c21,n1);   // (0,1)
        rot(c00,c10,c20,n0, c02,c12,c22,n2);   // (0,2)
        rot(c01,c11,c21,n1, c02,c12,c22,n2);   // (1,2)
    }

    // ---- U (descending by de Rijk) ----
    float i0 = frsq(fmaxf(n0, 1e-30f));
    float i1 = frsq(fmaxf(n1, 1e-30f));
    float u00 = c00*i0, u10 = c10*i0, u20 = c20*i0;
    float u01 = c01*i1, u11 = c11*i1, u21 = c21*i1;
    float u02 = fmaf(u10,u21, -u20*u11);       // u2 = u0 x u1
    float u12 = fmaf(u20,u01, -u00*u21);
    float u22 = fmaf(u00,u11, -u10*u01);

    // ---- V recovery: v_i = normalize(A^T u_i), v2 = v0 x v1 ----
    float q0 = fmaf(a00,u00, fmaf(a10,u10, a20*u20));   // (A^T u0)
    float q1 = fmaf(a01,u00, fmaf(a11,u10, a21*u20));
    float q2 = fmaf(a02,u00, fmaf(a12,u10, a22*u20));
    float m0 = fmaf(q0,q0, fmaf(q1,q1, q2*q2));
    float j0 = frsq(fmaxf(m0, 1e-30f));
    float v00 = q0*j0, v10 = q1*j0, v20 = q2*j0;

    q0 = fmaf(a00,u01, fmaf(a10,u11, a20*u21));         // (A^T u1)
    q1 = fmaf(a01,u01, fmaf(a11,u11, a21*u21));
    q2 = fmaf(a02,u01, fmaf(a12,u11, a22*u21));
    float m1 = fmaf(q0,q0, fmaf(q1,q1, q2*q2));
    float j1 = frsq(fmaxf(m1, 1e-30f));
    float v01 = q0*j1, v11 = q1*j1, v21 = q2*j1;

    float v02 = fmaf(v10,v21, -v20*v11);                // v2 = v0 x v1
    float v12 = fmaf(v20,v01, -v00*v21);
    float v22 = fmaf(v00,v11, -v10*v01);

    // third singular term coefficient (signed): s2 = u2^T A v2
    float w0 = fmaf(a00,v02, fmaf(a01,v12, a02*v22));
    float w1 = fmaf(a10,v02, fmaf(a11,v12, a12*v22));
    float w2 = fmaf(a20,v02, fmaf(a21,v12, a22*v22));
    float s2 = fmaf(u02,w0, fmaf(u12,w1, u22*w2));

    // ---- Drucker-Prager return mapping on log strains ----
    // log(max(sigma,0.05)) = 0.5*log(max(sigma^2,0.0025)): use carried n directly
    float e0 = 0.5f * __logf(fmaxf(n0, 0.0025f));
    float e1 = 0.5f * __logf(fmaxf(n1, 0.0025f));
    float e2 = __logf(fmaxf(fabsf(s2), 0.05f));
    float tr  = e0 + e1 + e2;
    float tr3 = tr * (1.0f / 3.0f);
    float h0 = e0 - tr3, h1 = e1 - tr3, h2 = e2 - tr3;
    float hn = fsqrt_r(fmaf(h0,h0, fmaf(h1,h1, h2*h2)));
    hn = fmaxf(hn, 1e-10f);
    float st = tr - coh * 3.0f;
    float dg = hn + ratio * st;
    float sc = fmaxf(dg, 0.0f) * frcp(hn);
    bool yield = st < 0.0f;
    float ec0 = yield ? fmaf(-sc, h0, e0) : coh;
    float ec1 = yield ? fmaf(-sc, h1, e1) : coh;
    float ec2 = yield ? fmaf(-sc, h2, e2) : coh;
    float f0 = __expf(ec0);
    float f1 = __expf(ec1);
    float f2 = copysignf(__expf(ec2), s2);     // fold third-term sign into scale

    // ---- F_corrected = sum_k f_k * u_k * v_k^T ----
    float w00 = u00*f0, w01 = u01*f1, w02 = u02*f2;
    float w10 = u10*f0, w11 = u11*f1, w12 = u12*f2;
    float w20 = u20*f0, w21 = u21*f1, w22 = u22*f2;
    float r00 = fmaf(w00,v00, fmaf(w01,v01, w02*v02));
    float r01 = fmaf(w00,v10, fmaf(w01,v11, w02*v12));
    float r02 = fmaf(w00,v20, fmaf(w01,v21, w02*v22));
    float r10 = fmaf(w10,v00, fmaf(w11,v01, w12*v02));
    float r11 = fmaf(w10,v10, fmaf(w11,v11, w12*v12));
    float r12 = fmaf(w10,v20, fmaf(w11,v21, w12*v22));
    float r20 = fmaf(w20,v00, fmaf(w21,v01, w22*v02));
    float r21 = fmaf(w20,v10, fmaf(w21,v11, w22*v12));
    float r22 = fmaf(w20,v20, fmaf(w21,v21, w22*v22));

    // ---- stage out through LDS, coalesced ----
    __syncthreads();   // all input-stage LDS reads complete before reuse
    if (valid) {
        float* p = lds + t_id * 9;
        p[0]=r00; p[1]=r01; p[2]=r02;
        p[3]=r10; p[4]=r11; p[5]=r12;
        p[6]=r20; p[7]=r21; p[8]=r22;
    }
    __syncthreads();

    #pragma unroll
    for (int j = 0; j < 3; ++j) {
        int idx = t_id + j * BLOCK;
        if (idx < F4PB) {
            int g4 = (base_f >> 2) + idx;
            int gf = g4 << 2;
            if (gf + 4 <= nfloats) {
                ((float4*)out)[g4] = ((float4*)lds)[idx];
            } else {
                #pragma unroll
                for (int k = 0; k < 4; ++k)
                    if (gf + k < nfloats) out[gf + k] = lds[idx * 4 + k];
            }
        }
    }
}

extern "C" void kernel_launch(void* const* d_in, const int* in_sizes, int n_in,
                              void* d_out, int out_size, void* d_ws, size_t ws_size,
                              hipStream_t stream) {
    const float* F = (const float*)d_in[0];
    const int n_elem = in_sizes[0] / 9;
    const int grid = (n_elem + BLOCK - 1) / BLOCK;
    dp_kernel<<<grid, BLOCK, 0, stream>>>(
        F,
        (const float*)d_in[1], (const float*)d_in[2],
        (const float*)d_in[3], (const float*)d_in[4],
        (float*)d_out, n_elem);
}